// Round 5
// baseline (7942.291 us; speedup 1.0000x reference)
//
#include <hip/hip_runtime.h>
#include <hip/hip_bf16.h>
#include <cstdint>
#include <cstddef>

#define DEV __device__ __forceinline__

static constexpr int D  = 768;
static constexpr int NH = 12;
static constexpr int NE = 4;
static constexpr int DH = 3072;
static constexpr int L  = 1024;
static constexpr int T  = 2048;
static constexpr int V  = 32000;
static constexpr int NL = 4;

// ------------------------------------------------------------- fp32 GEMM ----
// C[M,N] = A[M,K] @ B[K,N] (+bias), all fp32, B in native [K][N] layout.
// 128x128 tile, BK=16, 256 threads, 8x8 per-thread microtile.
// Per-z (blockIdx.z) offsets: A += z*aOff, B += z*bOff, out col += z*zCol,
// bias index = z*zBias + global_col.
// EPI: 0 = store; 1 = qkv (elu+1 for col<1536); 2 = out += acc+bias;
// 3 = srow[m][z] * gelu(acc+bias); 4 = atomicAdd (no bias).
template <int EPI>
__global__ __launch_bounds__(256) void k_fgemm(
    const float* __restrict__ A, int lda, long aOff,
    const float* __restrict__ B, int ldb, long bOff,
    const float* __restrict__ bias, int zBias,
    float* __restrict__ outp, int ldc, int zCol,
    const float* __restrict__ aux,
    int N, int Keff) {
  const int z = blockIdx.z;
  A += (size_t)z * (size_t)aOff;
  B += (size_t)z * (size_t)bOff;
  const int tid = threadIdx.x;
  const int tx = tid & 15;        // n-block
  const int ty = tid >> 4;        // m-block
  const int m0 = blockIdx.y * 128;
  const int n0 = blockIdx.x * 128;
  const int colBase = n0 + z * zCol;

  __shared__ float As[16 * 132];  // [kk][m], row stride 132
  __shared__ float Bs[16 * 132];  // [kk][n]

  float acc[8][8];
#pragma unroll
  for (int i = 0; i < 8; ++i)
#pragma unroll
    for (int j = 0; j < 8; ++j) acc[i][j] = 0.f;

  const int sk = tid & 15;   // k index for A staging
  const int sm = tid >> 4;   // m base for A staging

  for (int kt = 0; kt < Keff; kt += 16) {
    __syncthreads();
#pragma unroll
    for (int i = 0; i < 8; ++i) {
      const int m = sm + 16 * i;
      As[sk * 132 + m] = A[(size_t)(m0 + m) * lda + kt + sk];
    }
#pragma unroll
    for (int i = 0; i < 8; ++i) {
      const int idx = tid + 256 * i;
      const int kk = idx >> 7, n = idx & 127;
      Bs[kk * 132 + n] = B[(size_t)(kt + kk) * ldb + n0 + n];
    }
    __syncthreads();

#pragma unroll
    for (int kk = 0; kk < 16; ++kk) {
      const float4 a0 = *(const float4*)&As[kk * 132 + ty * 8];
      const float4 a1 = *(const float4*)&As[kk * 132 + ty * 8 + 4];
      const float4 b0 = *(const float4*)&Bs[kk * 132 + tx * 8];
      const float4 b1 = *(const float4*)&Bs[kk * 132 + tx * 8 + 4];
      const float av[8] = {a0.x, a0.y, a0.z, a0.w, a1.x, a1.y, a1.z, a1.w};
      const float bv[8] = {b0.x, b0.y, b0.z, b0.w, b1.x, b1.y, b1.z, b1.w};
#pragma unroll
      for (int i = 0; i < 8; ++i)
#pragma unroll
        for (int j = 0; j < 8; ++j) acc[i][j] += av[i] * bv[j];
    }
  }

#pragma unroll
  for (int j = 0; j < 8; ++j) {
    const int col = colBase + tx * 8 + j;
    float bvl = 0.f;
    if constexpr (EPI != 4) bvl = bias[zBias * z + col];
#pragma unroll
    for (int i = 0; i < 8; ++i) {
      const int mm = m0 + ty * 8 + i;
      float v = acc[i][j] + bvl;
      const size_t idx = (size_t)mm * ldc + col;
      if constexpr (EPI == 0) {
        outp[idx] = v;
      } else if constexpr (EPI == 1) {
        outp[idx] = (col < 1536) ? (v > 0.f ? v + 1.f : expf(v)) : v;
      } else if constexpr (EPI == 2) {
        outp[idx] += v;
      } else if constexpr (EPI == 3) {
        const float s  = aux[mm * 4 + z];
        const float gl = 0.5f * v * (1.f + erff(v * 0.70710678118654752f));
        outp[idx] = s * gl;
      } else {
        atomicAdd(outp + idx, v);
      }
    }
  }
}

// ------------------------------------------------------------ small kernels --
__global__ void k_embed(const int* __restrict__ tok,
                        const float* __restrict__ emb,
                        const float* __restrict__ pos, float* __restrict__ x) {
  const int idx = blockIdx.x * 256 + threadIdx.x;  // exactly T*D
  const int t = idx / D, d = idx - t * D;
  const int tk = tok[t];
  x[idx] = emb[(size_t)tk * D + d] + pos[(size_t)(t & (L - 1)) * D + d];
}

// LayerNorm fp32->fp32. If gw != nullptr also emit fp32 gate logits (+gb).
__global__ __launch_bounds__(256) void k_ln(const float* __restrict__ x,
                                            const float* __restrict__ g,
                                            const float* __restrict__ bb,
                                            float* __restrict__ xn,
                                            const float* __restrict__ gw,
                                            const float* __restrict__ gb,
                                            float* __restrict__ glog) {
  const int row = blockIdx.x, tid = threadIdx.x;
  const float* xr = x + (size_t)row * D;
  const float v0 = xr[tid], v1 = xr[tid + 256], v2 = xr[tid + 512];
  float s = v0 + v1 + v2, s2 = v0 * v0 + v1 * v1 + v2 * v2;
  for (int off = 1; off < 64; off <<= 1) {
    s += __shfl_xor(s, off);
    s2 += __shfl_xor(s2, off);
  }
  __shared__ float rs[4], rs2[4];
  const int w = tid >> 6;
  if ((tid & 63) == 0) { rs[w] = s; rs2[w] = s2; }
  __syncthreads();
  const float S = rs[0] + rs[1] + rs[2] + rs[3];
  const float S2 = rs2[0] + rs2[1] + rs2[2] + rs2[3];
  const float mean = S * (1.f / 768.f);
  const float var = fmaxf(S2 * (1.f / 768.f) - mean * mean, 0.f);
  const float rstd = rsqrtf(var + 1e-5f);
  const float o0 = (v0 - mean) * rstd * g[tid]       + bb[tid];
  const float o1 = (v1 - mean) * rstd * g[tid + 256] + bb[tid + 256];
  const float o2 = (v2 - mean) * rstd * g[tid + 512] + bb[tid + 512];
  float* xo = xn + (size_t)row * D;
  xo[tid] = o0;
  xo[tid + 256] = o1;
  xo[tid + 512] = o2;

  if (gw != nullptr) {
    const float4 ga = *(const float4*)&gw[tid * 4];
    const float4 gbv = *(const float4*)&gw[(tid + 256) * 4];
    const float4 gc = *(const float4*)&gw[(tid + 512) * 4];
    float p0 = o0 * ga.x + o1 * gbv.x + o2 * gc.x;
    float p1 = o0 * ga.y + o1 * gbv.y + o2 * gc.y;
    float p2 = o0 * ga.z + o1 * gbv.z + o2 * gc.z;
    float p3 = o0 * ga.w + o1 * gbv.w + o2 * gc.w;
    for (int off = 1; off < 64; off <<= 1) {
      p0 += __shfl_xor(p0, off);
      p1 += __shfl_xor(p1, off);
      p2 += __shfl_xor(p2, off);
      p3 += __shfl_xor(p3, off);
    }
    __shared__ float rg[4][4];
    if ((tid & 63) == 0) {
      rg[w][0] = p0; rg[w][1] = p1; rg[w][2] = p2; rg[w][3] = p3;
    }
    __syncthreads();
    if (tid == 0) {
      float* gl = glog + (size_t)row * 4;
#pragma unroll
      for (int e = 0; e < 4; ++e)
        gl[e] = rg[0][e] + rg[1][e] + rg[2][e] + rg[3][e] + gb[e];
    }
  }
}

// top-2 + softmax over 4 gate logits -> srow[T][4]
__global__ void k_topk(const float* __restrict__ glog,
                       float* __restrict__ srow) {
  const int t = blockIdx.x * 256 + threadIdx.x;  // exactly T
  float gv[4];
#pragma unroll
  for (int i = 0; i < 4; ++i) gv[i] = glog[t * 4 + i];
  int i1 = 0;
#pragma unroll
  for (int i = 1; i < 4; ++i)
    if (gv[i] > gv[i1]) i1 = i;
  int i2 = -1;
#pragma unroll
  for (int i = 0; i < 4; ++i) {
    if (i == i1) continue;
    if (i2 < 0 || gv[i] > gv[i2]) i2 = i;
  }
  const float e = expf(gv[i2] - gv[i1]);
  const float wa = 1.f / (1.f + e), wb = e / (1.f + e);
  float o[4] = {0.f, 0.f, 0.f, 0.f};
  o[i1] = wa;
  o[i2] = wb;
#pragma unroll
  for (int i = 0; i < 4; ++i) srow[t * 4 + i] = o[i];
}

__global__ void k_cat3(const float* __restrict__ a, const float* __restrict__ b,
                       const float* __restrict__ c, float* __restrict__ o) {
  const int i = blockIdx.x * 256 + threadIdx.x;  // exactly 2304
  o[i] = i < 768 ? a[i] : (i < 1536 ? b[i - 768] : c[i - 1536]);
}

// wqkv[k][j] (768x2304) from qw/kw/vw (each 768x768), fp32
__global__ void k_catW(const float* __restrict__ qw,
                       const float* __restrict__ kw,
                       const float* __restrict__ vw, float* __restrict__ o) {
  const int idx = blockIdx.x * 256 + threadIdx.x;  // exactly 768*2304
  const int k = idx / 2304, j = idx - k * 2304;
  float v;
  if (j < 768) v = qw[k * 768 + j];
  else if (j < 1536) v = kw[k * 768 + (j - 768)];
  else v = vw[k * 768 + (j - 1536)];
  o[idx] = v;
}

// Partial KV/Z over an L-chunk of 128 rows. part[c][bh][e*64+f], Z at +4096.
__global__ __launch_bounds__(256) void k_kvpart(const float* __restrict__ qkv,
                                                float* __restrict__ part) {
  const int bh = blockIdx.x;  // 0..23
  const int b = bh / NH, h = bh % NH;
  const int c = blockIdx.y;  // 0..7
  const int tid = threadIdx.x;
  __shared__ float kf[64], vv[64];
  float acc[16];
#pragma unroll
  for (int j = 0; j < 16; ++j) acc[j] = 0.f;
  float zacc = 0.f;
  const int e = tid >> 2;
  const int f0 = (tid & 3) * 16;
  const int t0 = b * L + c * 128;
  for (int i = 0; i < 128; ++i) {
    __syncthreads();
    const size_t rowb = (size_t)(t0 + i) * 2304;
    if (tid < 64) kf[tid] = qkv[rowb + 768 + h * 64 + tid];
    else if (tid < 128) vv[tid - 64] = qkv[rowb + 1536 + h * 64 + (tid - 64)];
    __syncthreads();
    const float ke = kf[e];
#pragma unroll
    for (int j = 0; j < 16; ++j) acc[j] += ke * vv[f0 + j];
    if (tid < 64) zacc += kf[tid];
  }
  const size_t base = ((size_t)c * 24 + bh) * 4160;
#pragma unroll
  for (int j = 0; j < 16; ++j) part[base + e * 64 + f0 + j] = acc[j];
  if (tid < 64) part[base + 4096 + tid] = zacc;
}

__global__ void k_kvred(const float* __restrict__ part, float* __restrict__ kv) {
  const int idx = blockIdx.x * 256 + threadIdx.x;  // exactly 24*4160
  float s = 0.f;
#pragma unroll
  for (int cc = 0; cc < 8; ++cc) s += part[(size_t)cc * 99840 + idx];
  kv[idx] = s;
}

__global__ __launch_bounds__(256) void k_attnout(const float* __restrict__ qkv,
                                                 const float* __restrict__ kv,
                                                 float* __restrict__ att) {
  const int t = blockIdx.x;
  const int b = t >> 10;
  const int tid = threadIdx.x;
  __shared__ float q[768];
  __shared__ float den[12];
  for (int i = tid; i < 768; i += 256) q[i] = qkv[(size_t)t * 2304 + i];
  __syncthreads();
  if (tid < 12) {
    const float* z = kv + ((size_t)(b * NH + tid)) * 4160 + 4096;
    float s = 0.f;
#pragma unroll
    for (int e = 0; e < 64; ++e) s += q[tid * 64 + e] * z[e];
    den[tid] = s + 1e-6f;
  }
  __syncthreads();
  for (int i = tid; i < 768; i += 256) {
    const int h = i >> 6, f = i & 63;
    const float* Kv = kv + ((size_t)(b * NH + h)) * 4160;
    float s = 0.f;
#pragma unroll
    for (int e = 0; e < 64; ++e) s += q[h * 64 + e] * Kv[e * 64 + f];
    att[(size_t)t * 768 + i] = s / den[h];
  }
}

// x += sum_e srow[t][e] * b2[e][n]
__global__ void k_moebias(float* __restrict__ x, const float* __restrict__ srow,
                          const float* __restrict__ b2l) {
  const int idx = blockIdx.x * 256 + threadIdx.x;  // exactly T*D
  const int t = idx / D, n = idx - t * D;
  const float* s = srow + t * 4;
  x[idx] += s[0] * b2l[n] + s[1] * b2l[D + n] + s[2] * b2l[2 * D + n] +
            s[3] * b2l[3 * D + n];
}

// ------------------------------------------------------------------ launch ---
extern "C" void kernel_launch(void* const* d_in, const int* in_sizes, int n_in,
                              void* d_out, int out_size, void* d_ws,
                              size_t ws_size, hipStream_t stream) {
  const int*   tokens = (const int*)d_in[0];
  const float* emb  = (const float*)d_in[1];
  const float* pos  = (const float*)d_in[2];
  const float* qw   = (const float*)d_in[3];
  const float* qb   = (const float*)d_in[4];
  const float* kw   = (const float*)d_in[5];
  const float* kb   = (const float*)d_in[6];
  const float* vw   = (const float*)d_in[7];
  const float* vb   = (const float*)d_in[8];
  const float* ow   = (const float*)d_in[9];
  const float* ob   = (const float*)d_in[10];
  const float* ln1g = (const float*)d_in[11];
  const float* ln1b = (const float*)d_in[12];
  const float* ln2g = (const float*)d_in[13];
  const float* ln2b = (const float*)d_in[14];
  const float* gw   = (const float*)d_in[15];
  const float* gb   = (const float*)d_in[16];
  const float* w1   = (const float*)d_in[17];
  const float* b1   = (const float*)d_in[18];
  const float* w2   = (const float*)d_in[19];
  const float* b2   = (const float*)d_in[20];
  const float* hw   = (const float*)d_in[21];
  const float* hb   = (const float*)d_in[22];

  char* p = (char*)d_ws;
  auto alloc = [&](size_t bytes) -> void* {
    void* r = (void*)p;
    p += (bytes + 255) & ~((size_t)255);
    return r;
  };
  float* x    = (float*)alloc((size_t)T * D * 4);          // 6.3 MB
  float* xn   = (float*)alloc((size_t)T * D * 4);          // 6.3 MB
  float* qkvb = (float*)alloc((size_t)T * 2304 * 4);       // 18.9 MB
  float* att  = (float*)alloc((size_t)T * D * 4);          // 6.3 MB
  float* kvp  = (float*)alloc((size_t)8 * 24 * 4160 * 4);  // 3.2 MB
  float* kv   = (float*)alloc((size_t)24 * 4160 * 4);      // 0.4 MB
  float* srow = (float*)alloc((size_t)T * 4 * 4);
  float* glog = (float*)alloc((size_t)T * 4 * 4);
  float* bqkv = (float*)alloc((size_t)2304 * 4);
  float* wqkv = (float*)alloc((size_t)D * 2304 * 4);       // 7.1 MB
  // hs [T][12288] fp32 = 100.7 MB lives in d_out (262 MB), overwritten by the
  // final head GEMM afterwards.
  float* hs = (float*)d_out;

  k_embed<<<dim3(6144), 256, 0, stream>>>(tokens, emb, pos, x);

  for (int l = 0; l < NL; ++l) {
    const size_t DD = (size_t)D * D;
    k_catW<<<dim3(6912), 256, 0, stream>>>(qw + l * DD, kw + l * DD,
                                           vw + l * DD, wqkv);
    k_cat3<<<dim3(9), 256, 0, stream>>>(qb + l * D, kb + l * D, vb + l * D,
                                        bqkv);

    // attention
    k_ln<<<dim3(T), 256, 0, stream>>>(x, ln1g + l * D, ln1b + l * D, xn,
                                      nullptr, nullptr, nullptr);
    k_fgemm<1><<<dim3(18, 16, 1), 256, 0, stream>>>(
        xn, D, 0, wqkv, 2304, 0, bqkv, 0, qkvb, 2304, 0, nullptr, 2304, D);
    k_kvpart<<<dim3(24, 8), 256, 0, stream>>>(qkvb, kvp);
    k_kvred<<<dim3(390), 256, 0, stream>>>(kvp, kv);
    k_attnout<<<dim3(T), 256, 0, stream>>>(qkvb, kv, att);
    k_fgemm<2><<<dim3(6, 16, 1), 256, 0, stream>>>(
        att, D, 0, ow + l * DD, D, 0, ob + l * D, 0, x, D, 0, nullptr, D, D);

    // MoE
    k_ln<<<dim3(T), 256, 0, stream>>>(x, ln2g + l * D, ln2b + l * D, xn,
                                      gw + (size_t)l * D * NE, gb + l * NE,
                                      glog);
    k_topk<<<dim3(8), 256, 0, stream>>>(glog, srow);
    k_fgemm<3><<<dim3(24, 16, 4), 256, 0, stream>>>(
        xn, D, 0, w1 + (size_t)l * NE * D * DH, DH, (long)D * DH,
        b1 + (size_t)l * NE * DH, DH, hs, 12288, DH, srow, DH, D);
    k_moebias<<<dim3(6144), 256, 0, stream>>>(x, srow,
                                              b2 + (size_t)l * NE * D);
    k_fgemm<4><<<dim3(6, 16, 4), 256, 0, stream>>>(
        hs, 12288, (long)DH, w2 + (size_t)l * NE * DH * D, D, (long)DH * D,
        nullptr, 0, x, D, 0, nullptr, D, DH);
  }

  // head: d_out = x @ hw + hb (hs scratch region is dead by now)
  k_fgemm<0><<<dim3(250, 16, 1), 256, 0, stream>>>(
      x, D, 0, hw, V, 0, hb, 0, (float*)d_out, V, 0, nullptr, V, D);
}